// Round 7
// baseline (153.287 us; speedup 1.0000x reference)
//
#include <hip/hip_runtime.h>

#define T_TEST 8192
#define BB 8
#define FF 100
#define HH 512

typedef __bf16 bf16x8 __attribute__((ext_vector_type(8)));
typedef float f32x16 __attribute__((ext_vector_type(16)));
typedef unsigned short u16;
typedef unsigned int u32;

__device__ __forceinline__ u16 f2bf(float f) {
    u32 u = __float_as_uint(f);
    u += 0x7fffu + ((u >> 16) & 1);   // RNE
    return (u16)(u >> 16);
}

__device__ __forceinline__ float nan2num(float v) {
    u32 u = __float_as_uint(v);
    if ((u & 0x7f800000u) == 0x7f800000u) {
        v = (u & 0x007fffffu) ? 0.f : ((u >> 31) ? -3.3895314e38f : 3.3895314e38f);
    }
    return v;
}

// ---- combined weight prep: 32x32x16 fragment-major layouts -------------
// B-frag for 32x32x16: B[k][n], n = lane&31, k = (lane>>5)*8 + j, 8 bf16/lane.
// w1f frag idx: ((b*8  + ks)*16 + n32)*64 + lane   (K=128 padded -> ks 0..7)
// w2f frag idx: ((b*32 + ks)*16 + n32)*64 + lane   (K=512        -> ks 0..31)
__global__ void prep_w(const float* __restrict__ w1, const float* __restrict__ w2,
                       u16* __restrict__ w1f, u16* __restrict__ w2f) {
    int bid = blockIdx.x;
    if (bid < 256) {                      // w1f: 65536 threads
        int t = bid * 256 + threadIdx.x;
        int lane = t & 63;
        int n32 = (t >> 6) & 15;
        int b = t >> 13;
        int n = n32 * 32 + (lane & 31);
        int kb = ((t >> 10) & 7) * 16 + (lane >> 5) * 8;
        u32 p[4];
#pragma unroll
        for (int jp = 0; jp < 4; ++jp) {
            int k0 = kb + jp * 2;
            float v0 = (k0 < FF)     ? w1[(b * FF + k0) * HH + n]     : 0.f;
            float v1 = (k0 + 1 < FF) ? w1[(b * FF + k0 + 1) * HH + n] : 0.f;
            p[jp] = (u32)f2bf(v0) | ((u32)f2bf(v1) << 16);
        }
        uint4 o = {p[0], p[1], p[2], p[3]};
        *(uint4*)(w1f + (size_t)t * 8) = o;   // t == frag index by construction
    } else {                              // w2f: 262144 threads
        int t = (bid - 256) * 256 + threadIdx.x;
        int lane = t & 63;
        int n32 = (t >> 6) & 15;
        int b = t >> 15;
        int n = n32 * 32 + (lane & 31);
        int kb = ((t >> 10) & 31) * 16 + (lane >> 5) * 8;
        u32 p[4];
#pragma unroll
        for (int jp = 0; jp < 4; ++jp) {
            int k0 = kb + jp * 2;
            float v0 = w2[(b * HH + k0) * HH + n];
            float v1 = w2[(b * HH + k0 + 1) * HH + n];
            p[jp] = (u32)f2bf(v0) | ((u32)f2bf(v1) << 16);
        }
        uint4 o = {p[0], p[1], p[2], p[3]};
        *(uint4*)(w2f + (size_t)t * 8) = o;
    }
}

// swizzled LDS indices: granule = 8 u16 = 16B; xor low-4 granule bits by row&15.
__device__ __forceinline__ int x_idx(int row, int k) {     // [64][128] bf16
    int g = k >> 3;
    int gp = g ^ (row & 15);               // 16 granules/row
    return row * 128 + gp * 8 + (k & 7);
}
__device__ __forceinline__ int h1_idx(int row, int col) {  // [64][512] bf16
    int g = col >> 3;
    int gp = (g & ~15) | ((g ^ row) & 15); // 64 granules/row
    return row * 512 + gp * 8 + (col & 7);
}

// ---- fused 3-layer MLP: 64 rows/block, 4 waves, wave = 2m x 4n32 tiles,
// ---- scalarized B addressing, depth-3 pipeline, K-phase stagger -------
__global__ __launch_bounds__(256, 2) void fused_mlp(
    const float* __restrict__ x, const u16* __restrict__ w1f,
    const float* __restrict__ b1, const u16* __restrict__ w2f,
    const float* __restrict__ b2, const float* __restrict__ w3,
    const float* __restrict__ b3, float* __restrict__ out) {
    __shared__ __align__(16) u16 h1_lds[64 * 512];   // 64 KB
    __shared__ __align__(16) u16 x_lds[64 * 128];    // 16 KB (reused as part[])

    const int tid = threadIdx.x;
    const int b = blockIdx.x;              // batch -> XCD affinity
    const int m0 = blockIdx.y * 64;
    const int lane = tid & 63;
    const int ws = __builtin_amdgcn_readfirstlane(tid >> 6);  // scalar wave id 0..3
    const int l31 = lane & 31, lh = lane >> 5;
    const int n32b = ws * 4;               // wave's n32 base (scalar)
    const int r1 = (ws * 2) & 7;           // layer-1 K-phase
    const int r2 = (ws * 8) & 31;          // layer-2 K-phase

    const bf16x8* W1 = (const bf16x8*)w1f + (size_t)b * (8 * 16 * 64);
    const bf16x8* W2 = (const bf16x8*)w2f + (size_t)b * (32 * 16 * 64);

    bf16x8 pa[3][2], pb[3][4];

    // layer-1 B prologue (stages 0,1) — in flight across x staging
#pragma unroll
    for (int s = 0; s < 2; ++s) {
        int k = (r1 + s) & 7;
#pragma unroll
        for (int ni = 0; ni < 4; ++ni)
            pb[s][ni] = W1[(k * 16 + n32b + ni) * 64 + lane];
    }

    // ---- stage x: 4 threads/row, bf16, swizzled, k 100..127 zeroed ----
    {
        int row = tid >> 2, sub = tid & 3;
        const float* xr = x + ((size_t)(m0 + row) * BB + b) * FF;
#pragma unroll
        for (int j = 0; j < 7; ++j) {
            int k = sub * 4 + j * 16;
            if (k < FF) {
                float4 v = *(const float4*)(xr + k);
                ushort4 h;
                h.x = f2bf(nan2num(v.x));
                h.y = f2bf(nan2num(v.y));
                h.z = f2bf(nan2num(v.z));
                h.w = f2bf(nan2num(v.w));
                *(ushort4*)(&x_lds[x_idx(row, k)]) = h;
            }
        }
        if (sub == 0) {
            ushort4 z = {0, 0, 0, 0};
            *(ushort4*)(&x_lds[x_idx(row, 100)]) = z;         // k 100..103
        } else {
            int4 z = {0, 0, 0, 0};
            *(int4*)(&x_lds[x_idx(row, 96 + sub * 8)]) = z;   // k 104..127
        }
    }
    __syncthreads();

    // ---- layer 1: depth-3 pipelined, K-phase r1 ----
    f32x16 acc1[2][4] = {};
#pragma unroll
    for (int s = 0; s < 2; ++s) {
        int k = (r1 + s) & 7;
#pragma unroll
        for (int mi = 0; mi < 2; ++mi)
            pa[s][mi] = *(const bf16x8*)(&x_lds[x_idx(mi * 32 + l31, (2 * k + lh) * 8)]);
    }
#pragma unroll
    for (int ks = 0; ks < 8; ++ks) {
        const int p = ks % 3;
        if (ks < 6) {
            const int f = (ks + 2) % 3;
            int kf = (ks + 2 + r1) & 7;
#pragma unroll
            for (int mi = 0; mi < 2; ++mi)
                pa[f][mi] = *(const bf16x8*)(&x_lds[x_idx(mi * 32 + l31, (2 * kf + lh) * 8)]);
#pragma unroll
            for (int ni = 0; ni < 4; ++ni)
                pb[f][ni] = W1[(kf * 16 + n32b + ni) * 64 + lane];
        }
#pragma unroll
        for (int ni = 0; ni < 4; ++ni) {
            acc1[0][ni] = __builtin_amdgcn_mfma_f32_32x32x16_bf16(pa[p][0], pb[p][ni], acc1[0][ni], 0, 0, 0);
            acc1[1][ni] = __builtin_amdgcn_mfma_f32_32x32x16_bf16(pa[p][1], pb[p][ni], acc1[1][ni], 0, 0, 0);
        }
    }

    // layer-2 B prologue — in flight across epilogue-1 + barrier
#pragma unroll
    for (int s = 0; s < 2; ++s) {
        int k = (r2 + s) & 31;
#pragma unroll
        for (int ni = 0; ni < 4; ++ni)
            pb[s][ni] = W2[(k * 16 + n32b + ni) * 64 + lane];
    }

    // ---- epilogue 1: relu(acc1+b1) -> h1_lds (paired dword writes) ----
    // C/D layout 32x32: col = lane&31, row = (r&3) + 8*(r>>2) + 4*(lane>>5)
    {
        u32* h32 = (u32*)h1_lds;
        const float* b1g = b1 + b * HH;
#pragma unroll
        for (int ni = 0; ni < 4; ++ni) {
            int n = (n32b + ni) * 32 + l31;
            float b1v = b1g[n];
            int ncol = n & ~1;
#pragma unroll
            for (int mi = 0; mi < 2; ++mi)
#pragma unroll
                for (int qd = 0; qd < 4; ++qd) {
                    u32 own01 = (u32)f2bf(fmaxf(acc1[mi][ni][qd * 4 + 0] + b1v, 0.f)) |
                                ((u32)f2bf(fmaxf(acc1[mi][ni][qd * 4 + 1] + b1v, 0.f)) << 16);
                    u32 own23 = (u32)f2bf(fmaxf(acc1[mi][ni][qd * 4 + 2] + b1v, 0.f)) |
                                ((u32)f2bf(fmaxf(acc1[mi][ni][qd * 4 + 3] + b1v, 0.f)) << 16);
                    u32 oth01 = __shfl_xor(own01, 1, 64);
                    u32 oth23 = __shfl_xor(own23, 1, 64);
                    int row0 = mi * 32 + qd * 8 + lh * 4;
                    if (!(lane & 1)) {
                        u32 d0 = (own01 & 0xffffu) | (oth01 << 16);
                        u32 d1 = (own01 >> 16) | (oth01 & 0xffff0000u);
                        h32[h1_idx(row0, ncol) >> 1] = d0;
                        h32[h1_idx(row0 + 1, ncol) >> 1] = d1;
                    } else {
                        u32 d2 = (oth23 & 0xffffu) | (own23 << 16);
                        u32 d3 = (oth23 >> 16) | (own23 & 0xffff0000u);
                        h32[h1_idx(row0 + 2, ncol) >> 1] = d2;
                        h32[h1_idx(row0 + 3, ncol) >> 1] = d3;
                    }
                }
        }
    }
    __syncthreads();   // h1 visible to all waves

    // ---- layer 2: full k=512, depth-3 pipelined, K-phase r2 ----
    f32x16 acc2[2][4] = {};
#pragma unroll
    for (int s = 0; s < 2; ++s) {
        int k = (r2 + s) & 31;
#pragma unroll
        for (int mi = 0; mi < 2; ++mi)
            pa[s][mi] = *(const bf16x8*)(&h1_lds[h1_idx(mi * 32 + l31, (2 * k + lh) * 8)]);
    }
#pragma unroll
    for (int ks = 0; ks < 32; ++ks) {
        const int p = ks % 3;
        if (ks < 30) {
            const int f = (ks + 2) % 3;
            int kf = (ks + 2 + r2) & 31;
#pragma unroll
            for (int mi = 0; mi < 2; ++mi)
                pa[f][mi] = *(const bf16x8*)(&h1_lds[h1_idx(mi * 32 + l31, (2 * kf + lh) * 8)]);
#pragma unroll
            for (int ni = 0; ni < 4; ++ni)
                pb[f][ni] = W2[(kf * 16 + n32b + ni) * 64 + lane];
        }
#pragma unroll
        for (int ni = 0; ni < 4; ++ni) {
            acc2[0][ni] = __builtin_amdgcn_mfma_f32_32x32x16_bf16(pa[p][0], pb[p][ni], acc2[0][ni], 0, 0, 0);
            acc2[1][ni] = __builtin_amdgcn_mfma_f32_32x32x16_bf16(pa[p][1], pb[p][ni], acc2[1][ni], 0, 0, 0);
        }
    }

    // ---- layer 3: fold n-slice in-register, reduce over 32 cols ----
    const float* b2g = b2 + b * HH;
    const float* w3g = w3 + b * HH;
    float b2v[4], w3v[4];
#pragma unroll
    for (int ni = 0; ni < 4; ++ni) {
        int n = (n32b + ni) * 32 + l31;
        b2v[ni] = b2g[n];
        w3v[ni] = w3g[n];
    }
    float* part = (float*)x_lds;   // [4][64]; x dead (all reads pre-h1-barrier)
#pragma unroll
    for (int mi = 0; mi < 2; ++mi)
#pragma unroll
        for (int r = 0; r < 16; ++r) {
            float v = 0.f;
#pragma unroll
            for (int ni = 0; ni < 4; ++ni)
                v += fmaxf(acc2[mi][ni][r] + b2v[ni], 0.f) * w3v[ni];
            v += __shfl_xor(v, 1, 64);
            v += __shfl_xor(v, 2, 64);
            v += __shfl_xor(v, 4, 64);
            v += __shfl_xor(v, 8, 64);
            v += __shfl_xor(v, 16, 64);
            if (l31 == 0)
                part[ws * 64 + mi * 32 + (r & 3) + 8 * (r >> 2) + 4 * lh] = v;
        }
    __syncthreads();
    if (tid < 64) {
        float s = b3[b];
#pragma unroll
        for (int ww = 0; ww < 4; ++ww) s += part[ww * 64 + tid];
        out[(size_t)(m0 + tid) * BB + b] = s;
    }
}

extern "C" void kernel_launch(void* const* d_in, const int* in_sizes, int n_in,
                              void* d_out, int out_size, void* d_ws, size_t ws_size,
                              hipStream_t stream) {
    const float* x  = (const float*)d_in[0];
    const float* w1 = (const float*)d_in[1];
    const float* b1 = (const float*)d_in[2];
    const float* w2 = (const float*)d_in[3];
    const float* b2 = (const float*)d_in[4];
    const float* w3 = (const float*)d_in[5];
    const float* b3 = (const float*)d_in[6];
    float* out = (float*)d_out;

    u16* w1f = (u16*)d_ws;                              // 8*8192 frags  = 1 MB
    u16* w2f = w1f + (size_t)BB * 8192 * 8;             // 8*32768 frags = 4 MB

    prep_w<<<1280, 256, 0, stream>>>(w1, w2, w1f, w2f);

    // grid.x = batch (XCD round-robin), grid.y = 64-row tile
    fused_mlp<<<dim3(BB, T_TEST / 64), 256, 0, stream>>>(
        x, w1f, b1, w2f, b2, w3, b3, out);
}

// Round 8
// 141.755 us; speedup vs baseline: 1.0814x; 1.0814x over previous
//
#include <hip/hip_runtime.h>

#define T_TEST 8192
#define BB 8
#define FF 100
#define HH 512

typedef __bf16 bf16x8 __attribute__((ext_vector_type(8)));
typedef float f32x16 __attribute__((ext_vector_type(16)));
typedef unsigned short u16;
typedef unsigned int u32;

__device__ __forceinline__ u16 f2bf(float f) {
    u32 u = __float_as_uint(f);
    u += 0x7fffu + ((u >> 16) & 1);   // RNE
    return (u16)(u >> 16);
}

__device__ __forceinline__ float nan2num(float v) {
    u32 u = __float_as_uint(v);
    if ((u & 0x7f800000u) == 0x7f800000u) {
        v = (u & 0x007fffffu) ? 0.f : ((u >> 31) ? -3.3895314e38f : 3.3895314e38f);
    }
    return v;
}

// ---- combined weight prep: 32x32x16 fragment-major layouts -------------
// B-frag for 32x32x16: B[k][n], n = lane&31, k = (lane>>5)*8 + j, 8 bf16/lane.
// w1f frag idx: ((b*8  + ks)*16 + n32)*64 + lane   (K=128 padded -> ks 0..7)
// w2f frag idx: ((b*32 + ks)*16 + n32)*64 + lane   (K=512        -> ks 0..31)
__global__ void prep_w(const float* __restrict__ w1, const float* __restrict__ w2,
                       u16* __restrict__ w1f, u16* __restrict__ w2f) {
    int bid = blockIdx.x;
    if (bid < 256) {                      // w1f: 65536 threads
        int t = bid * 256 + threadIdx.x;
        int lane = t & 63;
        int n32 = (t >> 6) & 15;
        int b = t >> 13;
        int n = n32 * 32 + (lane & 31);
        int kb = ((t >> 10) & 7) * 16 + (lane >> 5) * 8;
        u32 p[4];
#pragma unroll
        for (int jp = 0; jp < 4; ++jp) {
            int k0 = kb + jp * 2;
            float v0 = (k0 < FF)     ? w1[(b * FF + k0) * HH + n]     : 0.f;
            float v1 = (k0 + 1 < FF) ? w1[(b * FF + k0 + 1) * HH + n] : 0.f;
            p[jp] = (u32)f2bf(v0) | ((u32)f2bf(v1) << 16);
        }
        uint4 o = {p[0], p[1], p[2], p[3]};
        *(uint4*)(w1f + (size_t)t * 8) = o;   // t == frag index by construction
    } else {                              // w2f: 262144 threads
        int t = (bid - 256) * 256 + threadIdx.x;
        int lane = t & 63;
        int n32 = (t >> 6) & 15;
        int b = t >> 15;
        int n = n32 * 32 + (lane & 31);
        int kb = ((t >> 10) & 31) * 16 + (lane >> 5) * 8;
        u32 p[4];
#pragma unroll
        for (int jp = 0; jp < 4; ++jp) {
            int k0 = kb + jp * 2;
            float v0 = w2[(b * HH + k0) * HH + n];
            float v1 = w2[(b * HH + k0 + 1) * HH + n];
            p[jp] = (u32)f2bf(v0) | ((u32)f2bf(v1) << 16);
        }
        uint4 o = {p[0], p[1], p[2], p[3]};
        *(uint4*)(w2f + (size_t)t * 8) = o;
    }
}

// ---- fused 3-layer MLP: 64 rows/block, 8 waves (2 n32 each), 32x32x16,
// ---- frag-major LDS (A-loads = ds_read_b128 with imm offsets, zero VALU),
// ---- scalar B addressing, depth-3 pipeline, layer-2 K-stagger ---------
__global__ __launch_bounds__(512, 4) void fused_mlp(
    const float* __restrict__ x, const u16* __restrict__ w1f,
    const float* __restrict__ b1, const u16* __restrict__ w2f,
    const float* __restrict__ b2, const float* __restrict__ w3,
    const float* __restrict__ b3, float* __restrict__ out) {
    // LDS: x frags [0,16KB): fi1 = ks1*2+mi, 1KB each (A-frag order).
    //      h1 frags [16KB,80KB): fi = ks*2+mi, 1KB each (A-frag order).
    // A-frag element (m,k) of frag fi: byte fi*1024 + (((k&15)>>3)*32 + m)*16 + (k&7)*2
    __shared__ __align__(16) char lds[81920];
    u16* xf  = (u16*)lds;
    u16* h1f = (u16*)(lds + 16384);

    const int tid = threadIdx.x;
    const int b = blockIdx.x;              // batch -> XCD affinity
    const int m0 = blockIdx.y * 64;
    const int lane = tid & 63;
    const int ws = __builtin_amdgcn_readfirstlane(tid >> 6);  // scalar 0..7
    const int l31 = lane & 31, lh = lane >> 5;
    const int n32b = ws * 2;               // scalar n32 base
    const int r2 = ws * 4;                 // layer-2 K-phase (0..28)

    const bf16x8* W1 = (const bf16x8*)w1f + (size_t)b * 8192;
    const bf16x8* W2 = (const bf16x8*)w2f + (size_t)b * 32768;

    bf16x8 pa[3][2], pb[3][2];

    // layer-1 B prologue (ks=0,1) — in flight across x staging
#pragma unroll
    for (int s = 0; s < 2; ++s)
#pragma unroll
        for (int ni = 0; ni < 2; ++ni)
            pb[s][ni] = W1[(s * 16 + n32b + ni) * 64 + lane];

    // ---- stage x directly into A-frag order: thread = (row, ks1) ----
    {
        int row = tid >> 3, sub = tid & 7;     // sub = ks1, k = sub*16..+16
        int mi = row >> 5, m = row & 31;
        const float* xr = x + ((size_t)(m0 + row) * BB + b) * FF + sub * 16;
        u32 p[8];
#pragma unroll
        for (int i = 0; i < 8; ++i) p[i] = 0;
        if (sub <= 5) {
#pragma unroll
            for (int j = 0; j < 4; ++j) {
                float4 v = *(const float4*)(xr + j * 4);
                p[j * 2 + 0] = (u32)f2bf(nan2num(v.x)) | ((u32)f2bf(nan2num(v.y)) << 16);
                p[j * 2 + 1] = (u32)f2bf(nan2num(v.z)) | ((u32)f2bf(nan2num(v.w)) << 16);
            }
        } else if (sub == 6) {
            float4 v = *(const float4*)(xr);   // k 96..99
            p[0] = (u32)f2bf(nan2num(v.x)) | ((u32)f2bf(nan2num(v.y)) << 16);
            p[1] = (u32)f2bf(nan2num(v.z)) | ((u32)f2bf(nan2num(v.w)) << 16);
        }
        int fi1 = sub * 2 + mi;
        uint4 g0 = {p[0], p[1], p[2], p[3]};
        uint4 g1 = {p[4], p[5], p[6], p[7]};
        *(uint4*)(xf + (fi1 * 64 + m) * 8)      = g0;   // khalf 0
        *(uint4*)(xf + (fi1 * 64 + 32 + m) * 8) = g1;   // khalf 1
    }
    __syncthreads();

    // ---- layer 1: 8 k-steps, depth-3 pipeline, no stagger ----
    f32x16 acc1[2][2] = {};
#pragma unroll
    for (int s = 0; s < 2; ++s)
#pragma unroll
        for (int mi = 0; mi < 2; ++mi)
            pa[s][mi] = *(const bf16x8*)(xf + ((s * 2 + mi) * 64 + lane) * 8);
#pragma unroll
    for (int ks = 0; ks < 8; ++ks) {
        const int p = ks % 3;
        if (ks < 6) {
            const int f = (ks + 2) % 3;
#pragma unroll
            for (int mi = 0; mi < 2; ++mi)
                pa[f][mi] = *(const bf16x8*)(xf + (((ks + 2) * 2 + mi) * 64 + lane) * 8);
#pragma unroll
            for (int ni = 0; ni < 2; ++ni)
                pb[f][ni] = W1[((ks + 2) * 16 + n32b + ni) * 64 + lane];
        }
#pragma unroll
        for (int ni = 0; ni < 2; ++ni) {
            acc1[0][ni] = __builtin_amdgcn_mfma_f32_32x32x16_bf16(pa[p][0], pb[p][ni], acc1[0][ni], 0, 0, 0);
            acc1[1][ni] = __builtin_amdgcn_mfma_f32_32x32x16_bf16(pa[p][1], pb[p][ni], acc1[1][ni], 0, 0, 0);
        }
    }

    // layer-2 B prologue (ksp = r2, r2+1) — in flight across epilogue + barrier
#pragma unroll
    for (int s = 0; s < 2; ++s)
#pragma unroll
        for (int ni = 0; ni < 2; ++ni)
            pb[s][ni] = W2[((r2 + s) * 16 + n32b + ni) * 64 + lane];

    // ---- epilogue 1: relu(acc1+b1) -> h1f in A-frag order ----
    // C/D: col n = (n32b+ni)*32+l31, row = mi*32 + qd*8 + lh*4 + rr.
    // target byte = fi*1024 + (((n>>3)&1)*32 + row&31)*16 + (n&~1 &7)*2,
    //   fi = ((n32b+ni)*2 + (l31>>4))*2 + mi
    {
        const float* b1g = b1 + b * HH;
        char* hw = (char*)h1f + (l31 >> 4) * 2048 + ((l31 >> 3) & 1) * 512 +
                   (l31 & 6) * 2 + lh * 64 + n32b * 4096;
#pragma unroll
        for (int ni = 0; ni < 2; ++ni) {
            float b1v = b1g[(n32b + ni) * 32 + l31];
#pragma unroll
            for (int mi = 0; mi < 2; ++mi)
#pragma unroll
                for (int qd = 0; qd < 4; ++qd) {
                    u32 own01 = (u32)f2bf(fmaxf(acc1[mi][ni][qd * 4 + 0] + b1v, 0.f)) |
                                ((u32)f2bf(fmaxf(acc1[mi][ni][qd * 4 + 1] + b1v, 0.f)) << 16);
                    u32 own23 = (u32)f2bf(fmaxf(acc1[mi][ni][qd * 4 + 2] + b1v, 0.f)) |
                                ((u32)f2bf(fmaxf(acc1[mi][ni][qd * 4 + 3] + b1v, 0.f)) << 16);
                    u32 oth01 = __shfl_xor(own01, 1, 64);
                    u32 oth23 = __shfl_xor(own23, 1, 64);
                    char* base = hw + ni * 4096 + mi * 1024 + qd * 128;
                    if (!(lane & 1)) {
                        *(u32*)(base +  0) = (own01 & 0xffffu) | (oth01 << 16);        // rr=0
                        *(u32*)(base + 16) = (own01 >> 16) | (oth01 & 0xffff0000u);    // rr=1
                    } else {
                        *(u32*)(base + 32) = (oth23 & 0xffffu) | (own23 << 16);        // rr=2
                        *(u32*)(base + 48) = (oth23 >> 16) | (own23 & 0xffff0000u);    // rr=3
                    }
                }
        }
    }
    __syncthreads();   // h1 visible to all waves

    // ---- layer 2: 32 k-steps, K-phase r2 (two-base wrap select) ----
    f32x16 acc2[2][2] = {};
    const char* hv  = (const char*)h1f + r2 * 2048 + (size_t)lane * 16;
    const char* hvB = hv - 65536;
#pragma unroll
    for (int s = 0; s < 2; ++s)
#pragma unroll
        for (int mi = 0; mi < 2; ++mi)
            pa[s][mi] = *(const bf16x8*)(hv + s * 2048 + mi * 1024);
#pragma unroll
    for (int ks = 0; ks < 32; ++ks) {
        const int p = ks % 3;
        if (ks < 30) {
            const int f = (ks + 2) % 3;
            const char* hp = (ks + 2 + r2 < 32) ? hv : hvB;   // uniform select
#pragma unroll
            for (int mi = 0; mi < 2; ++mi)
                pa[f][mi] = *(const bf16x8*)(hp + (ks + 2) * 2048 + mi * 1024);
            int kspf = ks + 2 + r2;
            kspf -= (kspf >= 32) ? 32 : 0;                    // scalar
#pragma unroll
            for (int ni = 0; ni < 2; ++ni)
                pb[f][ni] = W2[(kspf * 16 + n32b + ni) * 64 + lane];
        }
#pragma unroll
        for (int ni = 0; ni < 2; ++ni) {
            acc2[0][ni] = __builtin_amdgcn_mfma_f32_32x32x16_bf16(pa[p][0], pb[p][ni], acc2[0][ni], 0, 0, 0);
            acc2[1][ni] = __builtin_amdgcn_mfma_f32_32x32x16_bf16(pa[p][1], pb[p][ni], acc2[1][ni], 0, 0, 0);
        }
    }

    // ---- layer 3: fold n-slice, reduce over 32 cols, cross-wave via LDS ----
    const float* b2g = b2 + b * HH;
    const float* w3g = w3 + b * HH;
    float b2v[2], w3v[2];
#pragma unroll
    for (int ni = 0; ni < 2; ++ni) {
        int n = (n32b + ni) * 32 + l31;
        b2v[ni] = b2g[n];
        w3v[ni] = w3g[n];
    }
    float* part = (float*)xf;   // [8][64]; x frags dead (reads pre-h1-barrier)
#pragma unroll
    for (int mi = 0; mi < 2; ++mi)
#pragma unroll
        for (int r = 0; r < 16; ++r) {
            float v = fmaxf(acc2[mi][0][r] + b2v[0], 0.f) * w3v[0] +
                      fmaxf(acc2[mi][1][r] + b2v[1], 0.f) * w3v[1];
            v += __shfl_xor(v, 1, 64);
            v += __shfl_xor(v, 2, 64);
            v += __shfl_xor(v, 4, 64);
            v += __shfl_xor(v, 8, 64);
            v += __shfl_xor(v, 16, 64);
            if (l31 == 0)
                part[ws * 64 + mi * 32 + (r & 3) + 8 * (r >> 2) + 4 * lh] = v;
        }
    __syncthreads();
    if (tid < 64) {
        float s = b3[b];
#pragma unroll
        for (int ww = 0; ww < 8; ++ww) s += part[ww * 64 + tid];
        out[(size_t)(m0 + tid) * BB + b] = s;
    }
}

extern "C" void kernel_launch(void* const* d_in, const int* in_sizes, int n_in,
                              void* d_out, int out_size, void* d_ws, size_t ws_size,
                              hipStream_t stream) {
    const float* x  = (const float*)d_in[0];
    const float* w1 = (const float*)d_in[1];
    const float* b1 = (const float*)d_in[2];
    const float* w2 = (const float*)d_in[3];
    const float* b2 = (const float*)d_in[4];
    const float* w3 = (const float*)d_in[5];
    const float* b3 = (const float*)d_in[6];
    float* out = (float*)d_out;

    u16* w1f = (u16*)d_ws;                              // 8*8192 frags  = 1 MB
    u16* w2f = w1f + (size_t)BB * 8192 * 8;             // 8*32768 frags = 4 MB

    prep_w<<<1280, 256, 0, stream>>>(w1, w2, w1f, w2f);

    // grid.x = batch (XCD round-robin), grid.y = 64-row tile
    fused_mlp<<<dim3(BB, T_TEST / 64), 512, 0, stream>>>(
        x, w1f, b1, w2f, b2, w3, b3, out);
}

// Round 9
// 138.167 us; speedup vs baseline: 1.1094x; 1.0260x over previous
//
#include <hip/hip_runtime.h>

#define T_TEST 8192
#define BB 8
#define FF 100
#define HH 512

typedef __bf16 bf16x8 __attribute__((ext_vector_type(8)));
typedef float f32x16 __attribute__((ext_vector_type(16)));
typedef unsigned short u16;
typedef unsigned int u32;

__device__ __forceinline__ u16 f2bf(float f) {
    u32 u = __float_as_uint(f);
    u += 0x7fffu + ((u >> 16) & 1);   // RNE
    return (u16)(u >> 16);
}

__device__ __forceinline__ float nan2num(float v) {
    u32 u = __float_as_uint(v);
    if ((u & 0x7f800000u) == 0x7f800000u) {
        v = (u & 0x007fffffu) ? 0.f : ((u >> 31) ? -3.3895314e38f : 3.3895314e38f);
    }
    return v;
}

// ---- combined weight prep: 32x32x16 fragment-major layouts -------------
__global__ void prep_w(const float* __restrict__ w1, const float* __restrict__ w2,
                       u16* __restrict__ w1f, u16* __restrict__ w2f) {
    int bid = blockIdx.x;
    if (bid < 256) {                      // w1f
        int t = bid * 256 + threadIdx.x;
        int lane = t & 63;
        int n32 = (t >> 6) & 15;
        int b = t >> 13;
        int n = n32 * 32 + (lane & 31);
        int kb = ((t >> 10) & 7) * 16 + (lane >> 5) * 8;
        u32 p[4];
#pragma unroll
        for (int jp = 0; jp < 4; ++jp) {
            int k0 = kb + jp * 2;
            float v0 = (k0 < FF)     ? w1[(b * FF + k0) * HH + n]     : 0.f;
            float v1 = (k0 + 1 < FF) ? w1[(b * FF + k0 + 1) * HH + n] : 0.f;
            p[jp] = (u32)f2bf(v0) | ((u32)f2bf(v1) << 16);
        }
        uint4 o = {p[0], p[1], p[2], p[3]};
        *(uint4*)(w1f + (size_t)t * 8) = o;
    } else {                              // w2f
        int t = (bid - 256) * 256 + threadIdx.x;
        int lane = t & 63;
        int n32 = (t >> 6) & 15;
        int b = t >> 15;
        int n = n32 * 32 + (lane & 31);
        int kb = ((t >> 10) & 31) * 16 + (lane >> 5) * 8;
        u32 p[4];
#pragma unroll
        for (int jp = 0; jp < 4; ++jp) {
            int k0 = kb + jp * 2;
            float v0 = w2[(b * HH + k0) * HH + n];
            float v1 = w2[(b * HH + k0 + 1) * HH + n];
            p[jp] = (u32)f2bf(v0) | ((u32)f2bf(v1) << 16);
        }
        uint4 o = {p[0], p[1], p[2], p[3]};
        *(uint4*)(w2f + (size_t)t * 8) = o;
    }
}

// ---- fused 3-layer MLP: 64 rows/block, 8 waves (2 n32 each), 32x32x16,
// ---- frag-major LDS, pb ring-4 / pa ring-2 (consume-then-refill), -----
// ---- grid transposed so tiles (not batches) round-robin the XCDs ------
__global__ __launch_bounds__(512, 4) void fused_mlp(
    const float* __restrict__ x, const u16* __restrict__ w1f,
    const float* __restrict__ b1, const u16* __restrict__ w2f,
    const float* __restrict__ b2, const float* __restrict__ w3,
    const float* __restrict__ b3, float* __restrict__ out) {
    __shared__ __align__(16) char lds[81920];
    u16* xf  = (u16*)lds;                  // x frags, 16 KB
    u16* h1f = (u16*)(lds + 16384);        // h1 frags, 64 KB

    const int tid = threadIdx.x;
    const int b = blockIdx.y;              // batch
    const int m0 = blockIdx.x * 64;        // tile -> XCD round-robin
    const int lane = tid & 63;
    const int ws = __builtin_amdgcn_readfirstlane(tid >> 6);
    const int l31 = lane & 31, lh = lane >> 5;
    const int n32b = ws * 2;
    const int r2 = ws * 4;                 // layer-2 K-phase

    const bf16x8* W1 = (const bf16x8*)w1f + (size_t)b * 8192;
    const bf16x8* W2 = (const bf16x8*)w2f + (size_t)b * 32768;

    bf16x8 pa[2][2], pb[4][2];

    // layer-1 B prologue: stages 0..3 in flight across x staging
#pragma unroll
    for (int s = 0; s < 4; ++s)
#pragma unroll
        for (int ni = 0; ni < 2; ++ni)
            pb[s][ni] = W1[(s * 16 + n32b + ni) * 64 + lane];

    // ---- stage x in A-frag order: thread = (row=lane, ks1=ws) ----
    {
        int row = lane, s = ws;
        int mi = row >> 5, m = row & 31;
        const float* xr = x + ((size_t)(m0 + row) * BB + b) * FF + s * 16;
        u32 p[8];
#pragma unroll
        for (int i = 0; i < 8; ++i) p[i] = 0;
        if (s <= 5) {
#pragma unroll
            for (int j = 0; j < 4; ++j) {
                float4 v = *(const float4*)(xr + j * 4);
                p[j * 2 + 0] = (u32)f2bf(nan2num(v.x)) | ((u32)f2bf(nan2num(v.y)) << 16);
                p[j * 2 + 1] = (u32)f2bf(nan2num(v.z)) | ((u32)f2bf(nan2num(v.w)) << 16);
            }
        } else if (s == 6) {
            float4 v = *(const float4*)(xr);
            p[0] = (u32)f2bf(nan2num(v.x)) | ((u32)f2bf(nan2num(v.y)) << 16);
            p[1] = (u32)f2bf(nan2num(v.z)) | ((u32)f2bf(nan2num(v.w)) << 16);
        }
        int fi1 = s * 2 + mi;
        uint4 g0 = {p[0], p[1], p[2], p[3]};
        uint4 g1 = {p[4], p[5], p[6], p[7]};
        *(uint4*)(xf + (fi1 * 64 + m) * 8)      = g0;
        *(uint4*)(xf + (fi1 * 64 + 32 + m) * 8) = g1;
    }
    __syncthreads();

    // ---- layer 1: 8 k-steps ----
    f32x16 acc1[2][2] = {};
#pragma unroll
    for (int s = 0; s < 2; ++s)
#pragma unroll
        for (int mi = 0; mi < 2; ++mi)
            pa[s][mi] = *(const bf16x8*)(xf + ((s * 2 + mi) * 64 + lane) * 8);
#pragma unroll
    for (int ks = 0; ks < 8; ++ks) {
        const int pA = ks & 1, pB = ks & 3;
        bf16x8 a0 = pa[pA][0], a1 = pa[pA][1];
        bf16x8 b0 = pb[pB][0], b1r = pb[pB][1];
        if (ks < 6) {
#pragma unroll
            for (int mi = 0; mi < 2; ++mi)
                pa[pA][mi] = *(const bf16x8*)(xf + (((ks + 2) * 2 + mi) * 64 + lane) * 8);
        }
        if (ks < 4) {
#pragma unroll
            for (int ni = 0; ni < 2; ++ni)
                pb[pB][ni] = W1[((ks + 4) * 16 + n32b + ni) * 64 + lane];
        }
        acc1[0][0] = __builtin_amdgcn_mfma_f32_32x32x16_bf16(a0, b0,  acc1[0][0], 0, 0, 0);
        acc1[0][1] = __builtin_amdgcn_mfma_f32_32x32x16_bf16(a0, b1r, acc1[0][1], 0, 0, 0);
        acc1[1][0] = __builtin_amdgcn_mfma_f32_32x32x16_bf16(a1, b0,  acc1[1][0], 0, 0, 0);
        acc1[1][1] = __builtin_amdgcn_mfma_f32_32x32x16_bf16(a1, b1r, acc1[1][1], 0, 0, 0);
    }

    // layer-2 B prologue: stages r2..r2+3
#pragma unroll
    for (int s = 0; s < 4; ++s) {
        int k = (r2 + s) & 31;
#pragma unroll
        for (int ni = 0; ni < 2; ++ni)
            pb[s][ni] = W2[(k * 16 + n32b + ni) * 64 + lane];
    }

    // ---- epilogue 1: relu(acc1+b1) -> h1f in A-frag order ----
    {
        const float* b1g = b1 + b * HH;
        char* hw = (char*)h1f + (l31 >> 4) * 2048 + ((l31 >> 3) & 1) * 512 +
                   (l31 & 6) * 2 + lh * 64 + n32b * 4096;
#pragma unroll
        for (int ni = 0; ni < 2; ++ni) {
            float b1v = b1g[(n32b + ni) * 32 + l31];
#pragma unroll
            for (int mi = 0; mi < 2; ++mi)
#pragma unroll
                for (int qd = 0; qd < 4; ++qd) {
                    u32 own01 = (u32)f2bf(fmaxf(acc1[mi][ni][qd * 4 + 0] + b1v, 0.f)) |
                                ((u32)f2bf(fmaxf(acc1[mi][ni][qd * 4 + 1] + b1v, 0.f)) << 16);
                    u32 own23 = (u32)f2bf(fmaxf(acc1[mi][ni][qd * 4 + 2] + b1v, 0.f)) |
                                ((u32)f2bf(fmaxf(acc1[mi][ni][qd * 4 + 3] + b1v, 0.f)) << 16);
                    u32 oth01 = __shfl_xor(own01, 1, 64);
                    u32 oth23 = __shfl_xor(own23, 1, 64);
                    char* base = hw + ni * 4096 + mi * 1024 + qd * 128;
                    if (!(lane & 1)) {
                        *(u32*)(base +  0) = (own01 & 0xffffu) | (oth01 << 16);
                        *(u32*)(base + 16) = (own01 >> 16) | (oth01 & 0xffff0000u);
                    } else {
                        *(u32*)(base + 32) = (oth23 & 0xffffu) | (own23 << 16);
                        *(u32*)(base + 48) = (oth23 >> 16) | (own23 & 0xffff0000u);
                    }
                }
        }
    }
    __syncthreads();

    // hoist layer-3 coefficients (latency hidden under layer 2)
    float b2v[2], w3v[2];
    {
        const float* b2g = b2 + b * HH;
        const float* w3g = w3 + b * HH;
#pragma unroll
        for (int ni = 0; ni < 2; ++ni) {
            int n = (n32b + ni) * 32 + l31;
            b2v[ni] = b2g[n];
            w3v[ni] = w3g[n];
        }
    }

    // ---- layer 2: 32 k-steps, K-phase r2 ----
    f32x16 acc2[2][2] = {};
    const char* hv  = (const char*)h1f + r2 * 2048 + (size_t)lane * 16;
    const char* hvB = hv - 65536;
#pragma unroll
    for (int s = 0; s < 2; ++s) {
        const char* hp = (s + r2 < 32) ? hv : hvB;
#pragma unroll
        for (int mi = 0; mi < 2; ++mi)
            pa[s][mi] = *(const bf16x8*)(hp + s * 2048 + mi * 1024);
    }
#pragma unroll
    for (int ks = 0; ks < 32; ++ks) {
        const int pA = ks & 1, pB = ks & 3;
        bf16x8 a0 = pa[pA][0], a1 = pa[pA][1];
        bf16x8 b0 = pb[pB][0], b1r = pb[pB][1];
        if (ks < 30) {
            const char* hp = (ks + 2 + r2 < 32) ? hv : hvB;
#pragma unroll
            for (int mi = 0; mi < 2; ++mi)
                pa[pA][mi] = *(const bf16x8*)(hp + (ks + 2) * 2048 + mi * 1024);
        }
        if (ks < 28) {
            int kspf = ks + 4 + r2;
            kspf -= (kspf >= 32) ? 32 : 0;
#pragma unroll
            for (int ni = 0; ni < 2; ++ni)
                pb[pB][ni] = W2[(kspf * 16 + n32b + ni) * 64 + lane];
        }
        acc2[0][0] = __builtin_amdgcn_mfma_f32_32x32x16_bf16(a0, b0,  acc2[0][0], 0, 0, 0);
        acc2[0][1] = __builtin_amdgcn_mfma_f32_32x32x16_bf16(a0, b1r, acc2[0][1], 0, 0, 0);
        acc2[1][0] = __builtin_amdgcn_mfma_f32_32x32x16_bf16(a1, b0,  acc2[1][0], 0, 0, 0);
        acc2[1][1] = __builtin_amdgcn_mfma_f32_32x32x16_bf16(a1, b1r, acc2[1][1], 0, 0, 0);
    }

    // ---- layer 3: fold, reduce over 32 cols, cross-wave via LDS ----
    float* part = (float*)xf;
#pragma unroll
    for (int mi = 0; mi < 2; ++mi)
#pragma unroll
        for (int r = 0; r < 16; ++r) {
            float v = fmaxf(acc2[mi][0][r] + b2v[0], 0.f) * w3v[0] +
                      fmaxf(acc2[mi][1][r] + b2v[1], 0.f) * w3v[1];
            v += __shfl_xor(v, 1, 64);
            v += __shfl_xor(v, 2, 64);
            v += __shfl_xor(v, 4, 64);
            v += __shfl_xor(v, 8, 64);
            v += __shfl_xor(v, 16, 64);
            if (l31 == 0)
                part[ws * 64 + mi * 32 + (r & 3) + 8 * (r >> 2) + 4 * lh] = v;
        }
    __syncthreads();
    if (tid < 64) {
        float s = b3[b];
#pragma unroll
        for (int ww = 0; ww < 8; ++ww) s += part[ww * 64 + tid];
        out[(size_t)(m0 + tid) * BB + b] = s;
    }
}

extern "C" void kernel_launch(void* const* d_in, const int* in_sizes, int n_in,
                              void* d_out, int out_size, void* d_ws, size_t ws_size,
                              hipStream_t stream) {
    const float* x  = (const float*)d_in[0];
    const float* w1 = (const float*)d_in[1];
    const float* b1 = (const float*)d_in[2];
    const float* w2 = (const float*)d_in[3];
    const float* b2 = (const float*)d_in[4];
    const float* w3 = (const float*)d_in[5];
    const float* b3 = (const float*)d_in[6];
    float* out = (float*)d_out;

    u16* w1f = (u16*)d_ws;                              // 1 MB
    u16* w2f = w1f + (size_t)BB * 8192 * 8;             // 4 MB

    prep_w<<<1280, 256, 0, stream>>>(w1, w2, w1f, w2f);

    // grid.x = 64-row tile (XCD round-robin), grid.y = batch
    fused_mlp<<<dim3(T_TEST / 64, BB), 512, 0, stream>>>(
        x, w1f, b1, w2f, b2, w3, b3, out);
}

// Round 10
// 137.080 us; speedup vs baseline: 1.1182x; 1.0079x over previous
//
#include <hip/hip_runtime.h>

#define T_TEST 8192
#define BB 8
#define FF 100
#define HH 512

typedef __bf16 bf16x8 __attribute__((ext_vector_type(8)));
typedef float f32x16 __attribute__((ext_vector_type(16)));
typedef unsigned short u16;
typedef unsigned int u32;

__device__ __forceinline__ u16 f2bf(float f) {
    u32 u = __float_as_uint(f);
    u += 0x7fffu + ((u >> 16) & 1);   // RNE
    return (u16)(u >> 16);
}

__device__ __forceinline__ float nan2num(float v) {
    u32 u = __float_as_uint(v);
    if ((u & 0x7f800000u) == 0x7f800000u) {
        v = (u & 0x007fffffu) ? 0.f : ((u >> 31) ? -3.3895314e38f : 3.3895314e38f);
    }
    return v;
}

// ---- combined weight prep: 32x32x16 fragment-major layouts -------------
// B-frag: B[k][n], n = lane&31, k = (lane>>5)*8 + j, 8 bf16/lane.
// w1f frag idx: ((b*8  + ks)*16 + n32)*64 + lane   (ks 0..7; kernel uses 0..6)
// w2f frag idx: ((b*32 + ks)*16 + n32)*64 + lane   (ks 0..31)
__global__ void prep_w(const float* __restrict__ w1, const float* __restrict__ w2,
                       u16* __restrict__ w1f, u16* __restrict__ w2f) {
    int bid = blockIdx.x;
    if (bid < 256) {                      // w1f
        int t = bid * 256 + threadIdx.x;
        int lane = t & 63;
        int n32 = (t >> 6) & 15;
        int b = t >> 13;
        int n = n32 * 32 + (lane & 31);
        int kb = ((t >> 10) & 7) * 16 + (lane >> 5) * 8;
        u32 p[4];
#pragma unroll
        for (int jp = 0; jp < 4; ++jp) {
            int k0 = kb + jp * 2;
            float v0 = (k0 < FF)     ? w1[(b * FF + k0) * HH + n]     : 0.f;
            float v1 = (k0 + 1 < FF) ? w1[(b * FF + k0 + 1) * HH + n] : 0.f;
            p[jp] = (u32)f2bf(v0) | ((u32)f2bf(v1) << 16);
        }
        uint4 o = {p[0], p[1], p[2], p[3]};
        *(uint4*)(w1f + (size_t)t * 8) = o;
    } else {                              // w2f
        int t = (bid - 256) * 256 + threadIdx.x;
        int lane = t & 63;
        int n32 = (t >> 6) & 15;
        int b = t >> 15;
        int n = n32 * 32 + (lane & 31);
        int kb = ((t >> 10) & 31) * 16 + (lane >> 5) * 8;
        u32 p[4];
#pragma unroll
        for (int jp = 0; jp < 4; ++jp) {
            int k0 = kb + jp * 2;
            float v0 = w2[(b * HH + k0) * HH + n];
            float v1 = w2[(b * HH + k0 + 1) * HH + n];
            p[jp] = (u32)f2bf(v0) | ((u32)f2bf(v1) << 16);
        }
        uint4 o = {p[0], p[1], p[2], p[3]};
        *(uint4*)(w2f + (size_t)t * 8) = o;
    }
}

// ---- fused 3-layer MLP: 64 rows/block, 8 waves (2 n32 each), 32x32x16,
// ---- frag-major LDS, pb ring-4 / pa ring-2, batch->XCD grid affinity --
__global__ __launch_bounds__(512, 4) void fused_mlp(
    const float* __restrict__ x, const u16* __restrict__ w1f,
    const float* __restrict__ b1, const u16* __restrict__ w2f,
    const float* __restrict__ b2, const float* __restrict__ w3,
    const float* __restrict__ b3, float* __restrict__ out) {
    __shared__ __align__(16) char lds[81920];
    u16* xf  = (u16*)lds;                  // x frags, 16 KB (fi = ks1*2+mi)
    u16* h1f = (u16*)(lds + 16384);        // h1 frags, 64 KB (fi = ks*2+mi)

    const int tid = threadIdx.x;
    const int b = blockIdx.x;              // batch -> XCD affinity (R8 proven)
    const int m0 = blockIdx.y * 64;
    const int lane = tid & 63;
    const int ws = __builtin_amdgcn_readfirstlane(tid >> 6);
    const int l31 = lane & 31, lh = lane >> 5;
    const int n32b = ws * 2;
    const int r2 = ws * 4;                 // layer-2 K-phase

    const bf16x8* W1 = (const bf16x8*)w1f + (size_t)b * 8192;
    const bf16x8* W2 = (const bf16x8*)w2f + (size_t)b * 32768;

    bf16x8 pa[2][2], pb[4][2];

    // layer-1 B prologue: stages 0..3 in flight across x staging
#pragma unroll
    for (int s = 0; s < 4; ++s)
#pragma unroll
        for (int ni = 0; ni < 2; ++ni)
            pb[s][ni] = W1[(s * 16 + n32b + ni) * 64 + lane];

    // hoist b1 (independent; latency hidden under staging + layer 1)
    float b1v[2];
    b1v[0] = b1[b * HH + (n32b + 0) * 32 + l31];
    b1v[1] = b1[b * HH + (n32b + 1) * 32 + l31];

    // ---- stage x in A-frag order: thread = (row=lane, ks1=ws), K1=112 ----
    if (ws < 7) {
        int row = lane, s = ws;
        int mi = row >> 5, m = row & 31;
        const float* xr = x + ((size_t)(m0 + row) * BB + b) * FF + s * 16;
        u32 p[8];
#pragma unroll
        for (int i = 0; i < 8; ++i) p[i] = 0;
        if (s <= 5) {
#pragma unroll
            for (int j = 0; j < 4; ++j) {
                float4 v = *(const float4*)(xr + j * 4);
                p[j * 2 + 0] = (u32)f2bf(nan2num(v.x)) | ((u32)f2bf(nan2num(v.y)) << 16);
                p[j * 2 + 1] = (u32)f2bf(nan2num(v.z)) | ((u32)f2bf(nan2num(v.w)) << 16);
            }
        } else {                           // s == 6: k 96..99 real, 100..111 zero
            float4 v = *(const float4*)(xr);
            p[0] = (u32)f2bf(nan2num(v.x)) | ((u32)f2bf(nan2num(v.y)) << 16);
            p[1] = (u32)f2bf(nan2num(v.z)) | ((u32)f2bf(nan2num(v.w)) << 16);
        }
        int fi1 = s * 2 + mi;
        uint4 g0 = {p[0], p[1], p[2], p[3]};
        uint4 g1 = {p[4], p[5], p[6], p[7]};
        *(uint4*)(xf + (fi1 * 64 + m) * 8)      = g0;   // khalf 0
        *(uint4*)(xf + (fi1 * 64 + 32 + m) * 8) = g1;   // khalf 1
    }
    __syncthreads();

    // ---- layer 1: 7 k-steps (K=112), pb ring-4, pa ring-2 ----
    f32x16 acc1[2][2] = {};
#pragma unroll
    for (int s = 0; s < 2; ++s)
#pragma unroll
        for (int mi = 0; mi < 2; ++mi)
            pa[s][mi] = *(const bf16x8*)(xf + ((s * 2 + mi) * 64 + lane) * 8);
#pragma unroll
    for (int ks = 0; ks < 7; ++ks) {
        const int pA = ks & 1, pB = ks & 3;
        bf16x8 a0 = pa[pA][0], a1 = pa[pA][1];
        bf16x8 b0 = pb[pB][0], b1r = pb[pB][1];
        if (ks < 5) {
#pragma unroll
            for (int mi = 0; mi < 2; ++mi)
                pa[pA][mi] = *(const bf16x8*)(xf + (((ks + 2) * 2 + mi) * 64 + lane) * 8);
        }
        if (ks < 3) {
#pragma unroll
            for (int ni = 0; ni < 2; ++ni)
                pb[pB][ni] = W1[((ks + 4) * 16 + n32b + ni) * 64 + lane];
        }
        acc1[0][0] = __builtin_amdgcn_mfma_f32_32x32x16_bf16(a0, b0,  acc1[0][0], 0, 0, 0);
        acc1[0][1] = __builtin_amdgcn_mfma_f32_32x32x16_bf16(a0, b1r, acc1[0][1], 0, 0, 0);
        acc1[1][0] = __builtin_amdgcn_mfma_f32_32x32x16_bf16(a1, b0,  acc1[1][0], 0, 0, 0);
        acc1[1][1] = __builtin_amdgcn_mfma_f32_32x32x16_bf16(a1, b1r, acc1[1][1], 0, 0, 0);
    }

    // layer-2 B prologue: stages r2..r2+3 (in flight across epilogue + barrier)
#pragma unroll
    for (int s = 0; s < 4; ++s) {
        int k = (r2 + s) & 31;
#pragma unroll
        for (int ni = 0; ni < 2; ++ni)
            pb[s][ni] = W2[(k * 16 + n32b + ni) * 64 + lane];
    }

    // ---- epilogue 1: relu(acc1+b1) -> h1f in A-frag order ----
    {
        char* hw = (char*)h1f + (l31 >> 4) * 2048 + ((l31 >> 3) & 1) * 512 +
                   (l31 & 6) * 2 + lh * 64 + n32b * 4096;
#pragma unroll
        for (int ni = 0; ni < 2; ++ni) {
#pragma unroll
            for (int mi = 0; mi < 2; ++mi)
#pragma unroll
                for (int qd = 0; qd < 4; ++qd) {
                    u32 own01 = (u32)f2bf(fmaxf(acc1[mi][ni][qd * 4 + 0] + b1v[ni], 0.f)) |
                                ((u32)f2bf(fmaxf(acc1[mi][ni][qd * 4 + 1] + b1v[ni], 0.f)) << 16);
                    u32 own23 = (u32)f2bf(fmaxf(acc1[mi][ni][qd * 4 + 2] + b1v[ni], 0.f)) |
                                ((u32)f2bf(fmaxf(acc1[mi][ni][qd * 4 + 3] + b1v[ni], 0.f)) << 16);
                    u32 oth01 = __shfl_xor(own01, 1, 64);
                    u32 oth23 = __shfl_xor(own23, 1, 64);
                    char* base = hw + ni * 4096 + mi * 1024 + qd * 128;
                    if (!(lane & 1)) {
                        *(u32*)(base +  0) = (own01 & 0xffffu) | (oth01 << 16);
                        *(u32*)(base + 16) = (own01 >> 16) | (oth01 & 0xffff0000u);
                    } else {
                        *(u32*)(base + 32) = (oth23 & 0xffffu) | (own23 << 16);
                        *(u32*)(base + 48) = (oth23 >> 16) | (own23 & 0xffff0000u);
                    }
                }
        }
    }
    __syncthreads();

    // hoist layer-3 coefficients (latency hidden under layer 2)
    float b2v[2], w3v[2];
#pragma unroll
    for (int ni = 0; ni < 2; ++ni) {
        int n = (n32b + ni) * 32 + l31;
        b2v[ni] = b2[b * HH + n];
        w3v[ni] = w3[b * HH + n];
    }

    // ---- layer 2: 32 k-steps, K-phase r2, pb ring-4, pa ring-2 ----
    f32x16 acc2[2][2] = {};
    const char* hv  = (const char*)h1f + r2 * 2048 + (size_t)lane * 16;
    const char* hvB = hv - 65536;
#pragma unroll
    for (int s = 0; s < 2; ++s) {
        const char* hp = (s + r2 < 32) ? hv : hvB;
#pragma unroll
        for (int mi = 0; mi < 2; ++mi)
            pa[s][mi] = *(const bf16x8*)(hp + s * 2048 + mi * 1024);
    }
#pragma unroll
    for (int ks = 0; ks < 32; ++ks) {
        const int pA = ks & 1, pB = ks & 3;
        bf16x8 a0 = pa[pA][0], a1 = pa[pA][1];
        bf16x8 b0 = pb[pB][0], b1r = pb[pB][1];
        if (ks < 30) {
            const char* hp = (ks + 2 + r2 < 32) ? hv : hvB;
#pragma unroll
            for (int mi = 0; mi < 2; ++mi)
                pa[pA][mi] = *(const bf16x8*)(hp + (ks + 2) * 2048 + mi * 1024);
        }
        if (ks < 28) {
            int kspf = ks + 4 + r2;
            kspf -= (kspf >= 32) ? 32 : 0;
#pragma unroll
            for (int ni = 0; ni < 2; ++ni)
                pb[pB][ni] = W2[(kspf * 16 + n32b + ni) * 64 + lane];
        }
        acc2[0][0] = __builtin_amdgcn_mfma_f32_32x32x16_bf16(a0, b0,  acc2[0][0], 0, 0, 0);
        acc2[0][1] = __builtin_amdgcn_mfma_f32_32x32x16_bf16(a0, b1r, acc2[0][1], 0, 0, 0);
        acc2[1][0] = __builtin_amdgcn_mfma_f32_32x32x16_bf16(a1, b0,  acc2[1][0], 0, 0, 0);
        acc2[1][1] = __builtin_amdgcn_mfma_f32_32x32x16_bf16(a1, b1r, acc2[1][1], 0, 0, 0);
    }

    // ---- layer 3: fold, reduce over 32 cols, cross-wave via LDS ----
    float* part = (float*)xf;
#pragma unroll
    for (int mi = 0; mi < 2; ++mi)
#pragma unroll
        for (int r = 0; r < 16; ++r) {
            float v = fmaxf(acc2[mi][0][r] + b2v[0], 0.f) * w3v[0] +
                      fmaxf(acc2[mi][1][r] + b2v[1], 0.f) * w3v[1];
            v += __shfl_xor(v, 1, 64);
            v += __shfl_xor(v, 2, 64);
            v += __shfl_xor(v, 4, 64);
            v += __shfl_xor(v, 8, 64);
            v += __shfl_xor(v, 16, 64);
            if (l31 == 0)
                part[ws * 64 + mi * 32 + (r & 3) + 8 * (r >> 2) + 4 * lh] = v;
        }
    __syncthreads();
    if (tid < 64) {
        float s = b3[b];
#pragma unroll
        for (int ww = 0; ww < 8; ++ww) s += part[ww * 64 + tid];
        out[(size_t)(m0 + tid) * BB + b] = s;
    }
}

extern "C" void kernel_launch(void* const* d_in, const int* in_sizes, int n_in,
                              void* d_out, int out_size, void* d_ws, size_t ws_size,
                              hipStream_t stream) {
    const float* x  = (const float*)d_in[0];
    const float* w1 = (const float*)d_in[1];
    const float* b1 = (const float*)d_in[2];
    const float* w2 = (const float*)d_in[3];
    const float* b2 = (const float*)d_in[4];
    const float* w3 = (const float*)d_in[5];
    const float* b3 = (const float*)d_in[6];
    float* out = (float*)d_out;

    u16* w1f = (u16*)d_ws;                              // 1 MB
    u16* w2f = w1f + (size_t)BB * 8192 * 8;             // 4 MB

    prep_w<<<1280, 256, 0, stream>>>(w1, w2, w1f, w2f);

    // grid.x = batch (XCD affinity), grid.y = 64-row tile
    fused_mlp<<<dim3(BB, T_TEST / 64), 512, 0, stream>>>(
        x, w1f, b1, w2f, b2, w3, b3, out);
}